// Round 12
// baseline (220.908 us; speedup 1.0000x reference)
//
#include <hip/hip_runtime.h>
#include <hip/hip_bf16.h>

#define NN 100000      // nodes
#define NE 1600000     // edges
#define NB 128         // graphs
#define NV 10000       // vocab
#define HD 128         // emb = hid = 128

#define NBUCK 782      // ceil(NN/128) buckets, bucket = dst >> 7
#define EBLK 512       // edge blocks for bucket passes (1024 threads each)
#define EPB (NE / EBLK)  // 3125 edges per block (exact)

using bf16x8 = __attribute__((ext_vector_type(8))) short;
using f32x4  = __attribute__((ext_vector_type(4))) float;
typedef __attribute__((ext_vector_type(8))) unsigned short ushortv8;
typedef __attribute__((ext_vector_type(8))) unsigned char ucharv8;
typedef float f32x2 __attribute__((ext_vector_type(2)));

__device__ __forceinline__ float bf2f(unsigned short b) {
  return __uint_as_float((unsigned)b << 16);
}
__device__ __forceinline__ unsigned short f2bf(float f) {
  __hip_bfloat16 h = __float2bfloat16(f);   // RNE
  return *reinterpret_cast<unsigned short*>(&h);
}
// f32 -> fp8 e4m3 (OCP on gfx950), single value -> low byte
__device__ __forceinline__ unsigned char f2fp8(float f) {
  return (unsigned char)(__builtin_amdgcn_cvt_pk_fp8_f32(f, 0.f, 0, false) & 0xff);
}
// positive f32 -> 15-bit sign-less bf16; pack with id (vocab 14b or src 17b)
__device__ __forceinline__ unsigned packSN(unsigned s, float v) {
  return (s << 15) | ((unsigned)f2bf(v) & 0x7fffu);
}
__device__ __forceinline__ float unpackN(unsigned u) {
  return __uint_as_float((u & 0x7fffu) << 16);
}
// acc[0..15] += c * fp8x16(u)
__device__ __forceinline__ void acc16(float* acc, uint4 u, float c) {
  f32x2 v;
  v = __builtin_amdgcn_cvt_pk_f32_fp8((int)u.x, false); acc[0] += c*v[0]; acc[1] += c*v[1];
  v = __builtin_amdgcn_cvt_pk_f32_fp8((int)u.x, true);  acc[2] += c*v[0]; acc[3] += c*v[1];
  v = __builtin_amdgcn_cvt_pk_f32_fp8((int)u.y, false); acc[4] += c*v[0]; acc[5] += c*v[1];
  v = __builtin_amdgcn_cvt_pk_f32_fp8((int)u.y, true);  acc[6] += c*v[0]; acc[7] += c*v[1];
  v = __builtin_amdgcn_cvt_pk_f32_fp8((int)u.z, false); acc[8] += c*v[0]; acc[9] += c*v[1];
  v = __builtin_amdgcn_cvt_pk_f32_fp8((int)u.z, true);  acc[10]+= c*v[0]; acc[11]+= c*v[1];
  v = __builtin_amdgcn_cvt_pk_f32_fp8((int)u.w, false); acc[12]+= c*v[0]; acc[13]+= c*v[1];
  v = __builtin_amdgcn_cvt_pk_f32_fp8((int)u.w, true);  acc[14]+= c*v[0]; acc[15]+= c*v[1];
}

// ============ bucketed counting-sort CSR build (no global atomics) ============

__global__ __launch_bounds__(1024) void k_bcount(const int* __restrict__ dst,
                                                 int* __restrict__ cntmat) {
  __shared__ int h[NBUCK];
  int t = threadIdx.x, blk = blockIdx.x;
  for (int i = t; i < NBUCK; i += 1024) h[i] = 0;
  __syncthreads();
  int base = blk * EPB;
  for (int i = t; i < EPB; i += 1024) atomicAdd(&h[dst[base + i] >> 7], 1);
  __syncthreads();
  for (int i = t; i < NBUCK; i += 1024) cntmat[(size_t)blk * NBUCK + i] = h[i];
}

// per-bucket exclusive scan over EBLK=512 block counts (2 values/thread)
__global__ __launch_bounds__(256) void k_cscan(int* __restrict__ cntmat,
                                               int* __restrict__ totals) {
  __shared__ int sh[256];
  int bu = blockIdx.x, t = threadIdx.x;
  int v0 = cntmat[(size_t)(2 * t) * NBUCK + bu];
  int v1 = cntmat[(size_t)(2 * t + 1) * NBUCK + bu];
  int s = v0 + v1;
  sh[t] = s;
  __syncthreads();
  #pragma unroll
  for (int off = 1; off < 256; off <<= 1) {
    int u = (t >= off) ? sh[t - off] : 0;
    __syncthreads();
    sh[t] += u;
    __syncthreads();
  }
  int pre = sh[t] - s;
  cntmat[(size_t)(2 * t) * NBUCK + bu] = pre;
  cntmat[(size_t)(2 * t + 1) * NBUCK + bu] = pre + v0;
  if (t == 255) totals[bu] = sh[255];
}

__global__ __launch_bounds__(1024) void k_tscan(const int* __restrict__ totals,
                                                int* __restrict__ bucketBase) {
  __shared__ int sh[1024];
  int t = threadIdx.x;
  int v = (t < NBUCK) ? totals[t] : 0;
  sh[t] = v;
  __syncthreads();
  #pragma unroll
  for (int off = 1; off < 1024; off <<= 1) {
    int u = (t >= off) ? sh[t - off] : 0;
    __syncthreads();
    sh[t] += u;
    __syncthreads();
  }
  if (t < NBUCK) bucketBase[t] = sh[t] - v;
  if (t == NBUCK - 1) bucketBase[NBUCK] = sh[t];   // = NE
}

// scatter edges into bucket-sorted array: one 8B store per edge
__global__ __launch_bounds__(1024) void k_bscatter(const int* __restrict__ src,
                                                   const int* __restrict__ dst,
                                                   const float* __restrict__ ew,
                                                   const int* __restrict__ cntmat,
                                                   const int* __restrict__ bucketBase,
                                                   uint2* __restrict__ spair) {
  __shared__ int off[NBUCK];
  int t = threadIdx.x, blk = blockIdx.x;
  for (int i = t; i < NBUCK; i += 1024)
    off[i] = bucketBase[i] + cntmat[(size_t)blk * NBUCK + i];
  __syncthreads();
  int base = blk * EPB;
  for (int i = t; i < EPB; i += 1024) {
    int e = base + i;
    int d = dst[e];
    unsigned pew = packSN((unsigned)src[e], ew[e]);
    int pos = atomicAdd(&off[d >> 7], 1);
    spair[pos] = make_uint2(pew, (unsigned)(d & 127));
  }
}

__global__ __launch_bounds__(256) void k_bdeg(const uint2* __restrict__ spair,
                                              const int* __restrict__ bucketBase,
                                              int* __restrict__ rowptr,
                                              float* __restrict__ dinv) {
  __shared__ int cnt[128];
  __shared__ float ws[128];
  __shared__ int sh[128];
  int bu = blockIdx.x, t = threadIdx.x;
  if (t < 128) { cnt[t] = 0; ws[t] = 0.f; }
  __syncthreads();
  int ebeg = bucketBase[bu], eend = bucketBase[bu + 1];
  for (int e = ebeg + t; e < eend; e += 256) {
    uint2 p = spair[e];
    atomicAdd(&cnt[p.y], 1);
    atomicAdd(&ws[p.y], unpackN(p.x));
  }
  __syncthreads();
  int v = 0;
  if (t < 128) { v = cnt[t]; sh[t] = v; }
  __syncthreads();
  #pragma unroll
  for (int off = 1; off < 128; off <<= 1) {
    int u = 0;
    if (t < 128 && t >= off) u = sh[t - off];
    __syncthreads();
    if (t < 128) sh[t] += u;
    __syncthreads();
  }
  if (t < 128) {
    int gid = (bu << 7) + t;
    if (gid < NN) {
      rowptr[gid] = ebeg + sh[t] - v;
      dinv[gid] = rsqrtf(1.0f + ws[t]);
    }
    if (gid == NN) rowptr[NN] = NE;   // bu=781, t=32
  }
}

// fill TWO packed CSR arrays: csrS = (src<<15|norm) for conv2,
// csrV = (xidx[src]<<15|norm) for conv1 (vocab id fits 14 bits).
__global__ __launch_bounds__(256) void k_bfill(const uint2* __restrict__ spair,
                                               const int* __restrict__ bucketBase,
                                               const int* __restrict__ rowptr,
                                               const float* __restrict__ dinv,
                                               const int* __restrict__ xidx,
                                               unsigned* __restrict__ csrS,
                                               unsigned* __restrict__ csrV) {
  __shared__ int cnt[128];
  __shared__ float sdv[128];
  __shared__ int srp[128];
  int bu = blockIdx.x, t = threadIdx.x;
  if (t < 128) {
    cnt[t] = 0;
    int gid = (bu << 7) + t;
    if (gid < NN) { sdv[t] = dinv[gid]; srp[t] = rowptr[gid]; }
  }
  __syncthreads();
  int ebeg = bucketBase[bu], eend = bucketBase[bu + 1];
  for (int e = ebeg + t; e < eend; e += 256) {
    uint2 p = spair[e];
    int dl = (int)p.y;
    unsigned s = p.x >> 15;
    float ewf = unpackN(p.x);
    int r = atomicAdd(&cnt[dl], 1);
    float nrm = dinv[s] * ewf * sdv[dl];
    int pos = srp[dl] + r;
    csrS[pos] = packSN(s, nrm);
    csrV[pos] = packSN((unsigned)xidx[s], nrm);
  }
}

// ---------------- W prep: both weights in one launch ----------------
__global__ void k_wprep2(const float* __restrict__ W1, const float* __restrict__ W2,
                         unsigned short* __restrict__ Wt1, unsigned short* __restrict__ Wt2) {
  int t = blockIdx.x * blockDim.x + threadIdx.x;  // 32768
  const float* W = (t < 16384) ? W1 : W2;
  unsigned short* Wt = (t < 16384) ? Wt1 : Wt2;
  int i = t & 16383;
  int k = i >> 7, n = i & 127;
  Wt[n * 128 + k] = f2bf(W[k * 128 + n]);
}

// ---------------- MFMA GEMM: C[M,128] = A[M,128] @ W[128,128], out fp8 ----------------
template <bool AF32>
__global__ __launch_bounds__(256) void k_gemm_mfma(const void* __restrict__ Av,
                                                   const unsigned short* __restrict__ Wt,
                                                   unsigned char* __restrict__ C, int M) {
  __shared__ unsigned char Cs[128][132];
  const int t = threadIdx.x;
  const int wave = t >> 6, lane = t & 63;
  const int lrow = lane & 15, lk = lane >> 4;
  const int row0 = blockIdx.x * 128;
  const int wrow = row0 + wave * 32;

  f32x4 acc[2][8];
  #pragma unroll
  for (int i = 0; i < 2; ++i)
    #pragma unroll
    for (int j = 0; j < 8; ++j) acc[i][j] = (f32x4){0.f, 0.f, 0.f, 0.f};

  #pragma unroll
  for (int kt = 0; kt < 4; ++kt) {
    bf16x8 a[2];
    #pragma unroll
    for (int rt = 0; rt < 2; ++rt) {
      int r = wrow + rt * 16 + lrow;
      bf16x8 av = (bf16x8){0, 0, 0, 0, 0, 0, 0, 0};
      if (r < M) {
        if (AF32) {
          const float* ap = (const float*)Av + (size_t)r * HD + kt * 32 + lk * 8;
          #pragma unroll
          for (int j = 0; j < 8; ++j) av[j] = (short)f2bf(ap[j]);
        } else {
          av = *(const bf16x8*)((const unsigned short*)Av + (size_t)r * HD + kt * 32 + lk * 8);
        }
      }
      a[rt] = av;
    }
    #pragma unroll
    for (int ct = 0; ct < 8; ++ct) {
      bf16x8 b = *(const bf16x8*)(Wt + (size_t)(ct * 16 + lrow) * HD + kt * 32 + lk * 8);
      acc[0][ct] = __builtin_amdgcn_mfma_f32_16x16x32_bf16(a[0], b, acc[0][ct], 0, 0, 0);
      acc[1][ct] = __builtin_amdgcn_mfma_f32_16x16x32_bf16(a[1], b, acc[1][ct], 0, 0, 0);
    }
  }

  #pragma unroll
  for (int rt = 0; rt < 2; ++rt)
    #pragma unroll
    for (int ct = 0; ct < 8; ++ct)
      #pragma unroll
      for (int reg = 0; reg < 4; ++reg) {
        int lr = wave * 32 + rt * 16 + lk * 4 + reg;
        Cs[lr][ct * 16 + lrow] = f2fp8(acc[rt][ct][reg]);
      }
  __syncthreads();

  #pragma unroll
  for (int i = 0; i < 8; ++i) {
    int idx = t + i * 256;       // 0..2047 uchar8 chunks
    int r = idx >> 4;
    int c = (idx & 15) * 8;
    int gr = row0 + r;
    if (gr < M)
      *(ucharv8*)(C + (size_t)gr * HD + c) = *(const ucharv8*)&Cs[r][c];
  }
}

// ---------------- pull aggregation, 8 lanes/node x 16B/lane, unroll-8 ----------------
// csr entry = 4B packed (id<<15 | bf16 norm); id = vocab (conv1) or node (conv2),
// pre-translated in k_bfill so the per-edge chain is csr -> row gather only.
// POOL=true: fused mean-pool partial (LDS run-reduce over sorted batch).
template <bool SELFIND, bool POOL>
__global__ __launch_bounds__(256) void k_agg8(const unsigned char* __restrict__ xw,
                                              const int* __restrict__ xidx,
                                              const int* __restrict__ rowptr,
                                              const unsigned* __restrict__ csr,
                                              const float* __restrict__ dinv,
                                              const float* __restrict__ bias,
                                              unsigned short* __restrict__ outp,
                                              const int* __restrict__ batch,
                                              float* __restrict__ sums) {
  int t = threadIdx.x;
  int n = blockIdx.x * 32 + (t >> 3);   // grid exact: 3125*32 = NN
  int lane = t & 7;                     // cols [lane*16, lane*16+16)
  int beg = rowptr[n], end = rowptr[n + 1];

  int sn = SELFIND ? xidx[n] : n;
  uint4 uself = *(const uint4*)(xw + (size_t)sn * HD + lane * 16);

  float acc[16];
  #pragma unroll
  for (int j = 0; j < 16; ++j) acc[j] = 0.f;

  int e = beg;
  int alignEnd = min(end, (beg + 3) & ~3);
  for (; e < alignEnd; ++e) {           // align e to 4 for uint4 csr loads
    unsigned u = csr[e];
    int s0 = (int)(u >> 15);
    float c0 = unpackN(u);
    uint4 u0 = *(const uint4*)(xw + (size_t)s0 * HD + lane * 16);
    acc16(acc, u0, c0);
  }
  for (; e + 7 < end; e += 8) {         // unroll-8: 8 row gathers in flight
    uint4 qa = *(const uint4*)(csr + e);
    uint4 qb = *(const uint4*)(csr + e + 4);
    int s0 = (int)(qa.x >> 15), s1 = (int)(qa.y >> 15);
    int s2 = (int)(qa.z >> 15), s3 = (int)(qa.w >> 15);
    int s4 = (int)(qb.x >> 15), s5 = (int)(qb.y >> 15);
    int s6 = (int)(qb.z >> 15), s7 = (int)(qb.w >> 15);
    uint4 u0 = *(const uint4*)(xw + (size_t)s0 * HD + lane * 16);
    uint4 u1 = *(const uint4*)(xw + (size_t)s1 * HD + lane * 16);
    uint4 u2 = *(const uint4*)(xw + (size_t)s2 * HD + lane * 16);
    uint4 u3 = *(const uint4*)(xw + (size_t)s3 * HD + lane * 16);
    uint4 u4 = *(const uint4*)(xw + (size_t)s4 * HD + lane * 16);
    uint4 u5 = *(const uint4*)(xw + (size_t)s5 * HD + lane * 16);
    uint4 u6 = *(const uint4*)(xw + (size_t)s6 * HD + lane * 16);
    uint4 u7 = *(const uint4*)(xw + (size_t)s7 * HD + lane * 16);
    acc16(acc, u0, unpackN(qa.x)); acc16(acc, u1, unpackN(qa.y));
    acc16(acc, u2, unpackN(qa.z)); acc16(acc, u3, unpackN(qa.w));
    acc16(acc, u4, unpackN(qb.x)); acc16(acc, u5, unpackN(qb.y));
    acc16(acc, u6, unpackN(qb.z)); acc16(acc, u7, unpackN(qb.w));
  }
  if (e + 3 < end) {                    // one unroll-4 step
    uint4 q = *(const uint4*)(csr + e);
    int s0 = (int)(q.x >> 15), s1 = (int)(q.y >> 15);
    int s2 = (int)(q.z >> 15), s3 = (int)(q.w >> 15);
    uint4 u0 = *(const uint4*)(xw + (size_t)s0 * HD + lane * 16);
    uint4 u1 = *(const uint4*)(xw + (size_t)s1 * HD + lane * 16);
    uint4 u2 = *(const uint4*)(xw + (size_t)s2 * HD + lane * 16);
    uint4 u3 = *(const uint4*)(xw + (size_t)s3 * HD + lane * 16);
    acc16(acc, u0, unpackN(q.x)); acc16(acc, u1, unpackN(q.y));
    acc16(acc, u2, unpackN(q.z)); acc16(acc, u3, unpackN(q.w));
    e += 4;
  }
  for (; e < end; ++e) {                // <=3 scalar
    unsigned u = csr[e];
    int s0 = (int)(u >> 15);
    float c0 = unpackN(u);
    uint4 u0 = *(const uint4*)(xw + (size_t)s0 * HD + lane * 16);
    acc16(acc, u0, c0);
  }

  float d = dinv[n];
  acc16(acc, uself, d * d);

  const float4* bp = reinterpret_cast<const float4*>(bias + lane * 16);
  float4 b0 = bp[0], b1 = bp[1], b2 = bp[2], b3 = bp[3];
  float o[16];
  o[0]  = fmaxf(acc[0]  + b0.x, 0.f); o[1]  = fmaxf(acc[1]  + b0.y, 0.f);
  o[2]  = fmaxf(acc[2]  + b0.z, 0.f); o[3]  = fmaxf(acc[3]  + b0.w, 0.f);
  o[4]  = fmaxf(acc[4]  + b1.x, 0.f); o[5]  = fmaxf(acc[5]  + b1.y, 0.f);
  o[6]  = fmaxf(acc[6]  + b1.z, 0.f); o[7]  = fmaxf(acc[7]  + b1.w, 0.f);
  o[8]  = fmaxf(acc[8]  + b2.x, 0.f); o[9]  = fmaxf(acc[9]  + b2.y, 0.f);
  o[10] = fmaxf(acc[10] + b2.z, 0.f); o[11] = fmaxf(acc[11] + b2.w, 0.f);
  o[12] = fmaxf(acc[12] + b3.x, 0.f); o[13] = fmaxf(acc[13] + b3.y, 0.f);
  o[14] = fmaxf(acc[14] + b3.z, 0.f); o[15] = fmaxf(acc[15] + b3.w, 0.f);

  if constexpr (!POOL) {
    ushortv8 r0, r1;
    #pragma unroll
    for (int j = 0; j < 8; ++j) { r0[j] = f2bf(o[j]); r1[j] = f2bf(o[8 + j]); }
    *(ushortv8*)(outp + (size_t)n * HD + lane * 16) = r0;
    *(ushortv8*)(outp + (size_t)n * HD + lane * 16 + 8) = r1;
  } else {
    __shared__ float pool[32][132];   // 132: 2-way max bank aliasing on writes
    __shared__ int ib[32];
    int nl = t >> 3;
    #pragma unroll
    for (int j = 0; j < 16; ++j) pool[nl][lane * 16 + j] = o[j];
    if (t < 32) ib[t] = batch[blockIdx.x * 32 + t];
    __syncthreads();
    if (t < 128) {
      float a = 0.f;
      int c = t;
      #pragma unroll 4
      for (int i = 0; i < 32; ++i) {
        a += pool[i][c];
        if (i == 31 || ib[i + 1] != ib[i]) {
          atomicAdd(&sums[(size_t)ib[i] * HD + c], a);
          a = 0.f;
        }
      }
    }
  }
}

// ---------------- zero sums + counts ----------------
__global__ __launch_bounds__(256) void k_zero_counts(float* __restrict__ sums,
                                                     const int* __restrict__ batch,
                                                     float* __restrict__ cnt) {
  int i = blockIdx.x * blockDim.x + threadIdx.x;
  if (i < NB * HD) sums[i] = 0.f;
  if (blockIdx.x == 0 && threadIdx.x < NB) {
    int b = threadIdx.x;
    auto lb = [&](int v) {
      int lo = 0, hi = NN;
      while (lo < hi) { int m = (lo + hi) >> 1; if (batch[m] < v) lo = m + 1; else hi = m; }
      return lo;
    };
    cnt[b] = (float)(lb(b + 1) - lb(b));
  }
}

// ---------------- MLP head + softmax ----------------
__global__ __launch_bounds__(64) void k_head(const float* __restrict__ sums,
                                             const float* __restrict__ cnt,
                                             const float* __restrict__ W1,
                                             const float* __restrict__ b1,
                                             const float* __restrict__ W2,
                                             const float* __restrict__ b2,
                                             float* __restrict__ out) {
  int g = blockIdx.x, t = threadIdx.x;  // 64 threads
  __shared__ float gv[128];
  __shared__ float h[64];
  __shared__ float logits[2];
  float c = fmaxf(cnt[g], 1.0f);
  gv[t] = sums[g * HD + t] / c;
  gv[t + 64] = sums[g * HD + 64 + t] / c;
  __syncthreads();
  float acc = b1[t];
  for (int k = 0; k < 128; ++k) acc += gv[k] * W1[k * 64 + t];
  h[t] = fmaxf(acc, 0.f);
  __syncthreads();
  if (t < 2) {
    float a = b2[t];
    for (int j = 0; j < 64; ++j) a += h[j] * W2[j * 2 + t];
    logits[t] = a;
  }
  __syncthreads();
  if (t < 2) {
    float m = fmaxf(logits[0], logits[1]);
    float e0 = __expf(logits[0] - m), e1 = __expf(logits[1] - m);
    out[g * 2 + t] = (t == 0 ? e0 : e1) / (e0 + e1);
  }
}

// ---------------- launch ----------------
extern "C" void kernel_launch(void* const* d_in, const int* in_sizes, int n_in,
                              void* d_out, int out_size, void* d_ws, size_t ws_size,
                              hipStream_t stream) {
  const int*   x_idx = (const int*)d_in[0];
  const int*   eidx  = (const int*)d_in[1];
  const float* ew    = (const float*)d_in[2];
  const int*   batch = (const int*)d_in[3];
  const float* emb   = (const float*)d_in[4];
  const float* W1    = (const float*)d_in[5];
  const float* b1    = (const float*)d_in[6];
  const float* W2    = (const float*)d_in[7];
  const float* b2    = (const float*)d_in[8];
  const float* mW1   = (const float*)d_in[9];
  const float* mb1   = (const float*)d_in[10];
  const float* mW2   = (const float*)d_in[11];
  const float* mb2   = (const float*)d_in[12];
  const int* src = eidx;
  const int* dst = eidx + NE;
  float* out = (float*)d_out;

  char* ws = (char*)d_ws;
  size_t off = 0;
  auto alloc = [&](size_t bytes) {
    void* p = ws + off;
    off += (bytes + 255) & ~(size_t)255;
    return p;
  };
  int*   cntmat     = (int*)alloc((size_t)EBLK * NBUCK * 4);   // 1.6 MB
  int*   totals     = (int*)alloc((size_t)NBUCK * 4);
  int*   bucketBase = (int*)alloc((size_t)(NBUCK + 1) * 4);
  int*   rowptr     = (int*)alloc((size_t)(NN + 1) * 4);
  float* dinv       = (float*)alloc((size_t)NN * 4);
  unsigned* csrS    = (unsigned*)alloc((size_t)NE * 4);        // (src|norm)
  unsigned* csrV    = (unsigned*)alloc((size_t)NE * 4);        // (vocab|norm)
  unsigned short* Wt1  = (unsigned short*)alloc((size_t)HD * HD * 2);
  unsigned short* Wt2  = (unsigned short*)alloc((size_t)HD * HD * 2);
  unsigned char* embW  = (unsigned char*)alloc((size_t)NV * HD);   // fp8
  unsigned char* bufA  = (unsigned char*)alloc((size_t)NN * HD);   // fp8
  float* sums    = (float*)alloc((size_t)NB * HD * 4);
  float* cnt     = (float*)alloc((size_t)NB * 4);
  // union: spair (12.8MB) lives only until k_bfill; bufB (25.6MB) written after
  char* unionReg = (char*)alloc((size_t)NN * HD * 2);
  uint2* spair = (uint2*)unionReg;
  unsigned short* bufB = (unsigned short*)unionReg;

  // ---- CSR build via bucketed counting sort (zero global atomics) ----
  k_bcount<<<EBLK, 1024, 0, stream>>>(dst, cntmat);
  k_cscan<<<NBUCK, 256, 0, stream>>>(cntmat, totals);
  k_tscan<<<1, 1024, 0, stream>>>(totals, bucketBase);
  k_bscatter<<<EBLK, 1024, 0, stream>>>(src, dst, ew, cntmat, bucketBase, spair);
  k_bdeg<<<NBUCK, 256, 0, stream>>>(spair, bucketBase, rowptr, dinv);
  k_bfill<<<NBUCK, 256, 0, stream>>>(spair, bucketBase, rowptr, dinv, x_idx, csrS, csrV);

  // weight prep (transpose + bf16, both weights in one launch)
  k_wprep2<<<128, 256, 0, stream>>>(W1, W2, Wt1, Wt2);

  // embW = fp8(emb_table @ W1)
  k_gemm_mfma<true><<<(NV + 127) / 128, 256, 0, stream>>>(emb, Wt1, embW, NV);

  // zero sums + counts (before fused-pool agg)
  k_zero_counts<<<64, 256, 0, stream>>>(sums, batch, cnt);

  // conv1: bufB = bf16(relu(agg(embW via csrV) + b1))
  k_agg8<true, false><<<NN / 32, 256, 0, stream>>>(
      embW, x_idx, rowptr, csrV, dinv, b1, bufB, nullptr, nullptr);

  // conv2: bufA = fp8(h1 @ W2) ; fused agg+mean-pool partials into sums
  k_gemm_mfma<false><<<(NN + 127) / 128, 256, 0, stream>>>(bufB, Wt2, bufA, NN);
  k_agg8<false, true><<<NN / 32, 256, 0, stream>>>(
      bufA, nullptr, rowptr, csrS, dinv, b2, nullptr, batch, sums);

  // head
  k_head<<<NB, 64, 0, stream>>>(sums, cnt, mW1, mb1, mW2, mb2, out);
}

// Round 13
// 194.126 us; speedup vs baseline: 1.1380x; 1.1380x over previous
//
#include <hip/hip_runtime.h>
#include <hip/hip_bf16.h>

#define NN 100000      // nodes
#define NE 1600000     // edges
#define NB 128         // graphs
#define NV 10000       // vocab
#define HD 128         // emb = hid = 128

#define NBUCK 782      // ceil(NN/128) buckets, bucket = dst >> 7
#define EBLK 512       // edge blocks for bucket passes (1024 threads each)
#define EPB (NE / EBLK)  // 3125 edges per block (exact)

using bf16x8 = __attribute__((ext_vector_type(8))) short;
using f32x4  = __attribute__((ext_vector_type(4))) float;
typedef __attribute__((ext_vector_type(8))) unsigned short ushortv8;
typedef __attribute__((ext_vector_type(8))) unsigned char ucharv8;
typedef float f32x2 __attribute__((ext_vector_type(2)));

__device__ __forceinline__ float bf2f(unsigned short b) {
  return __uint_as_float((unsigned)b << 16);
}
__device__ __forceinline__ unsigned short f2bf(float f) {
  __hip_bfloat16 h = __float2bfloat16(f);   // RNE
  return *reinterpret_cast<unsigned short*>(&h);
}
// f32 -> fp8 e4m3 (OCP on gfx950), single value -> low byte
__device__ __forceinline__ unsigned char f2fp8(float f) {
  return (unsigned char)(__builtin_amdgcn_cvt_pk_fp8_f32(f, 0.f, 0, false) & 0xff);
}
// positive f32 -> 15-bit sign-less bf16; pack with id (vocab 14b or src 17b)
__device__ __forceinline__ unsigned packSN(unsigned s, float v) {
  return (s << 15) | ((unsigned)f2bf(v) & 0x7fffu);
}
__device__ __forceinline__ float unpackN(unsigned u) {
  return __uint_as_float((u & 0x7fffu) << 16);
}
// acc[0..15] += c * fp8x16(u)
__device__ __forceinline__ void acc16(float* acc, uint4 u, float c) {
  f32x2 v;
  v = __builtin_amdgcn_cvt_pk_f32_fp8((int)u.x, false); acc[0] += c*v[0]; acc[1] += c*v[1];
  v = __builtin_amdgcn_cvt_pk_f32_fp8((int)u.x, true);  acc[2] += c*v[0]; acc[3] += c*v[1];
  v = __builtin_amdgcn_cvt_pk_f32_fp8((int)u.y, false); acc[4] += c*v[0]; acc[5] += c*v[1];
  v = __builtin_amdgcn_cvt_pk_f32_fp8((int)u.y, true);  acc[6] += c*v[0]; acc[7] += c*v[1];
  v = __builtin_amdgcn_cvt_pk_f32_fp8((int)u.z, false); acc[8] += c*v[0]; acc[9] += c*v[1];
  v = __builtin_amdgcn_cvt_pk_f32_fp8((int)u.z, true);  acc[10]+= c*v[0]; acc[11]+= c*v[1];
  v = __builtin_amdgcn_cvt_pk_f32_fp8((int)u.w, false); acc[12]+= c*v[0]; acc[13]+= c*v[1];
  v = __builtin_amdgcn_cvt_pk_f32_fp8((int)u.w, true);  acc[14]+= c*v[0]; acc[15]+= c*v[1];
}

// ============ bucketed counting-sort CSR build (no global atomics) ============

__global__ __launch_bounds__(1024) void k_bcount(const int* __restrict__ dst,
                                                 int* __restrict__ cntmat) {
  __shared__ int h[NBUCK];
  int t = threadIdx.x, blk = blockIdx.x;
  for (int i = t; i < NBUCK; i += 1024) h[i] = 0;
  __syncthreads();
  int base = blk * EPB;
  for (int i = t; i < EPB; i += 1024) atomicAdd(&h[dst[base + i] >> 7], 1);
  __syncthreads();
  for (int i = t; i < NBUCK; i += 1024) cntmat[(size_t)blk * NBUCK + i] = h[i];
}

// per-bucket exclusive scan over EBLK=512 block counts (2 values/thread)
__global__ __launch_bounds__(256) void k_cscan(int* __restrict__ cntmat,
                                               int* __restrict__ totals) {
  __shared__ int sh[256];
  int bu = blockIdx.x, t = threadIdx.x;
  int v0 = cntmat[(size_t)(2 * t) * NBUCK + bu];
  int v1 = cntmat[(size_t)(2 * t + 1) * NBUCK + bu];
  int s = v0 + v1;
  sh[t] = s;
  __syncthreads();
  #pragma unroll
  for (int off = 1; off < 256; off <<= 1) {
    int u = (t >= off) ? sh[t - off] : 0;
    __syncthreads();
    sh[t] += u;
    __syncthreads();
  }
  int pre = sh[t] - s;
  cntmat[(size_t)(2 * t) * NBUCK + bu] = pre;
  cntmat[(size_t)(2 * t + 1) * NBUCK + bu] = pre + v0;
  if (t == 255) totals[bu] = sh[255];
}

__global__ __launch_bounds__(1024) void k_tscan(const int* __restrict__ totals,
                                                int* __restrict__ bucketBase) {
  __shared__ int sh[1024];
  int t = threadIdx.x;
  int v = (t < NBUCK) ? totals[t] : 0;
  sh[t] = v;
  __syncthreads();
  #pragma unroll
  for (int off = 1; off < 1024; off <<= 1) {
    int u = (t >= off) ? sh[t - off] : 0;
    __syncthreads();
    sh[t] += u;
    __syncthreads();
  }
  if (t < NBUCK) bucketBase[t] = sh[t] - v;
  if (t == NBUCK - 1) bucketBase[NBUCK] = sh[t];   // = NE
}

// scatter edges into bucket-sorted array: one 8B store per edge
__global__ __launch_bounds__(1024) void k_bscatter(const int* __restrict__ src,
                                                   const int* __restrict__ dst,
                                                   const float* __restrict__ ew,
                                                   const int* __restrict__ cntmat,
                                                   const int* __restrict__ bucketBase,
                                                   uint2* __restrict__ spair) {
  __shared__ int off[NBUCK];
  int t = threadIdx.x, blk = blockIdx.x;
  for (int i = t; i < NBUCK; i += 1024)
    off[i] = bucketBase[i] + cntmat[(size_t)blk * NBUCK + i];
  __syncthreads();
  int base = blk * EPB;
  for (int i = t; i < EPB; i += 1024) {
    int e = base + i;
    int d = dst[e];
    unsigned pew = packSN((unsigned)src[e], ew[e]);
    int pos = atomicAdd(&off[d >> 7], 1);
    spair[pos] = make_uint2(pew, (unsigned)(d & 127));
  }
}

__global__ __launch_bounds__(256) void k_bdeg(const uint2* __restrict__ spair,
                                              const int* __restrict__ bucketBase,
                                              int* __restrict__ rowptr,
                                              float* __restrict__ dinv) {
  __shared__ int cnt[128];
  __shared__ float ws[128];
  __shared__ int sh[128];
  int bu = blockIdx.x, t = threadIdx.x;
  if (t < 128) { cnt[t] = 0; ws[t] = 0.f; }
  __syncthreads();
  int ebeg = bucketBase[bu], eend = bucketBase[bu + 1];
  for (int e = ebeg + t; e < eend; e += 256) {
    uint2 p = spair[e];
    atomicAdd(&cnt[p.y], 1);
    atomicAdd(&ws[p.y], unpackN(p.x));
  }
  __syncthreads();
  int v = 0;
  if (t < 128) { v = cnt[t]; sh[t] = v; }
  __syncthreads();
  #pragma unroll
  for (int off = 1; off < 128; off <<= 1) {
    int u = 0;
    if (t < 128 && t >= off) u = sh[t - off];
    __syncthreads();
    if (t < 128) sh[t] += u;
    __syncthreads();
  }
  if (t < 128) {
    int gid = (bu << 7) + t;
    if (gid < NN) {
      rowptr[gid] = ebeg + sh[t] - v;
      dinv[gid] = rsqrtf(1.0f + ws[t]);
    }
    if (gid == NN) rowptr[NN] = NE;   // bu=781, t=32
  }
}

__global__ __launch_bounds__(256) void k_bfill(const uint2* __restrict__ spair,
                                               const int* __restrict__ bucketBase,
                                               const int* __restrict__ rowptr,
                                               const float* __restrict__ dinv,
                                               unsigned* __restrict__ csr) {
  __shared__ int cnt[128];
  __shared__ float sdv[128];
  __shared__ int srp[128];
  int bu = blockIdx.x, t = threadIdx.x;
  if (t < 128) {
    cnt[t] = 0;
    int gid = (bu << 7) + t;
    if (gid < NN) { sdv[t] = dinv[gid]; srp[t] = rowptr[gid]; }
  }
  __syncthreads();
  int ebeg = bucketBase[bu], eend = bucketBase[bu + 1];
  for (int e = ebeg + t; e < eend; e += 256) {
    uint2 p = spair[e];
    int dl = (int)p.y;
    unsigned s = p.x >> 15;
    float ewf = unpackN(p.x);
    int r = atomicAdd(&cnt[dl], 1);
    float nrm = dinv[s] * ewf * sdv[dl];
    csr[srp[dl] + r] = packSN(s, nrm);
  }
}

// translate csrS (node id) -> csrV (vocab id); coalesced, fully parallel
__global__ void k_trans(const unsigned* __restrict__ csrS,
                        const int* __restrict__ xidx,
                        unsigned* __restrict__ csrV) {
  int i = blockIdx.x * blockDim.x + threadIdx.x;
  if (i < NE) {
    unsigned u = csrS[i];
    csrV[i] = ((unsigned)xidx[u >> 15] << 15) | (u & 0x7fffu);
  }
}

// ---------------- W prep: both weights in one launch ----------------
__global__ void k_wprep2(const float* __restrict__ W1, const float* __restrict__ W2,
                         unsigned short* __restrict__ Wt1, unsigned short* __restrict__ Wt2) {
  int t = blockIdx.x * blockDim.x + threadIdx.x;  // 32768
  const float* W = (t < 16384) ? W1 : W2;
  unsigned short* Wt = (t < 16384) ? Wt1 : Wt2;
  int i = t & 16383;
  int k = i >> 7, n = i & 127;
  Wt[n * 128 + k] = f2bf(W[k * 128 + n]);
}

// ---------------- MFMA GEMM: C[M,128] = A[M,128] @ W[128,128], out fp8 ----------------
template <bool AF32>
__global__ __launch_bounds__(256) void k_gemm_mfma(const void* __restrict__ Av,
                                                   const unsigned short* __restrict__ Wt,
                                                   unsigned char* __restrict__ C, int M) {
  __shared__ unsigned char Cs[128][132];
  const int t = threadIdx.x;
  const int wave = t >> 6, lane = t & 63;
  const int lrow = lane & 15, lk = lane >> 4;
  const int row0 = blockIdx.x * 128;
  const int wrow = row0 + wave * 32;

  f32x4 acc[2][8];
  #pragma unroll
  for (int i = 0; i < 2; ++i)
    #pragma unroll
    for (int j = 0; j < 8; ++j) acc[i][j] = (f32x4){0.f, 0.f, 0.f, 0.f};

  #pragma unroll
  for (int kt = 0; kt < 4; ++kt) {
    bf16x8 a[2];
    #pragma unroll
    for (int rt = 0; rt < 2; ++rt) {
      int r = wrow + rt * 16 + lrow;
      bf16x8 av = (bf16x8){0, 0, 0, 0, 0, 0, 0, 0};
      if (r < M) {
        if (AF32) {
          const float* ap = (const float*)Av + (size_t)r * HD + kt * 32 + lk * 8;
          #pragma unroll
          for (int j = 0; j < 8; ++j) av[j] = (short)f2bf(ap[j]);
        } else {
          av = *(const bf16x8*)((const unsigned short*)Av + (size_t)r * HD + kt * 32 + lk * 8);
        }
      }
      a[rt] = av;
    }
    #pragma unroll
    for (int ct = 0; ct < 8; ++ct) {
      bf16x8 b = *(const bf16x8*)(Wt + (size_t)(ct * 16 + lrow) * HD + kt * 32 + lk * 8);
      acc[0][ct] = __builtin_amdgcn_mfma_f32_16x16x32_bf16(a[0], b, acc[0][ct], 0, 0, 0);
      acc[1][ct] = __builtin_amdgcn_mfma_f32_16x16x32_bf16(a[1], b, acc[1][ct], 0, 0, 0);
    }
  }

  #pragma unroll
  for (int rt = 0; rt < 2; ++rt)
    #pragma unroll
    for (int ct = 0; ct < 8; ++ct)
      #pragma unroll
      for (int reg = 0; reg < 4; ++reg) {
        int lr = wave * 32 + rt * 16 + lk * 4 + reg;
        Cs[lr][ct * 16 + lrow] = f2fp8(acc[rt][ct][reg]);
      }
  __syncthreads();

  #pragma unroll
  for (int i = 0; i < 8; ++i) {
    int idx = t + i * 256;       // 0..2047 uchar8 chunks
    int r = idx >> 4;
    int c = (idx & 15) * 8;
    int gr = row0 + r;
    if (gr < M)
      *(ucharv8*)(C + (size_t)gr * HD + c) = *(const ucharv8*)&Cs[r][c];
  }
}

// ---------------- pull aggregation, 8 lanes/node x 16B/lane ----------------
// csr pre-translated (vocab id for conv1, node id for conv2): per-edge chain is
// csr -> gather only. csr quad loads software-pipelined (prefetch next quad).
// POOL=true: fused mean-pool partial (LDS run-reduce over sorted batch).
template <bool SELFIND, bool POOL>
__global__ __launch_bounds__(256) void k_agg8(const unsigned char* __restrict__ xw,
                                              const int* __restrict__ xidx,
                                              const int* __restrict__ rowptr,
                                              const unsigned* __restrict__ csr,
                                              const float* __restrict__ dinv,
                                              const float* __restrict__ bias,
                                              unsigned short* __restrict__ outp,
                                              const int* __restrict__ batch,
                                              float* __restrict__ sums) {
  int t = threadIdx.x;
  int n = blockIdx.x * 32 + (t >> 3);   // grid exact: 3125*32 = NN
  int lane = t & 7;                     // cols [lane*16, lane*16+16)
  int beg = rowptr[n], end = rowptr[n + 1];

  int sn = SELFIND ? xidx[n] : n;
  uint4 uself = *(const uint4*)(xw + (size_t)sn * HD + lane * 16);

  float acc[16];
  #pragma unroll
  for (int j = 0; j < 16; ++j) acc[j] = 0.f;

  auto quad = [&](uint4 q) {
    int s0 = (int)(q.x >> 15), s1 = (int)(q.y >> 15);
    int s2 = (int)(q.z >> 15), s3 = (int)(q.w >> 15);
    uint4 u0 = *(const uint4*)(xw + (size_t)s0 * HD + lane * 16);
    uint4 u1 = *(const uint4*)(xw + (size_t)s1 * HD + lane * 16);
    uint4 u2 = *(const uint4*)(xw + (size_t)s2 * HD + lane * 16);
    uint4 u3 = *(const uint4*)(xw + (size_t)s3 * HD + lane * 16);
    acc16(acc, u0, unpackN(q.x)); acc16(acc, u1, unpackN(q.y));
    acc16(acc, u2, unpackN(q.z)); acc16(acc, u3, unpackN(q.w));
  };

  int e = beg;
  int alignEnd = min(end, (beg + 3) & ~3);
  for (; e < alignEnd; ++e) {           // align e to 4 for uint4 csr loads
    unsigned u = csr[e];
    int s0 = (int)(u >> 15);
    float c0 = unpackN(u);
    uint4 u0 = *(const uint4*)(xw + (size_t)s0 * HD + lane * 16);
    acc16(acc, u0, c0);
  }
  int nquad = (end - e) >> 2;
  if (nquad > 0) {                      // software-pipelined quads
    uint4 q = *(const uint4*)(csr + e);
    for (int i = 1; i < nquad; ++i) {
      uint4 qn = *(const uint4*)(csr + e + 4 * i);   // prefetch next quad
      quad(q);
      q = qn;
    }
    quad(q);
    e += nquad * 4;
  }
  for (; e < end; ++e) {                // <=3 scalar tail
    unsigned u = csr[e];
    int s0 = (int)(u >> 15);
    float c0 = unpackN(u);
    uint4 u0 = *(const uint4*)(xw + (size_t)s0 * HD + lane * 16);
    acc16(acc, u0, c0);
  }

  float d = dinv[n];
  acc16(acc, uself, d * d);

  const float4* bp = reinterpret_cast<const float4*>(bias + lane * 16);
  float4 b0 = bp[0], b1 = bp[1], b2 = bp[2], b3 = bp[3];
  float o[16];
  o[0]  = fmaxf(acc[0]  + b0.x, 0.f); o[1]  = fmaxf(acc[1]  + b0.y, 0.f);
  o[2]  = fmaxf(acc[2]  + b0.z, 0.f); o[3]  = fmaxf(acc[3]  + b0.w, 0.f);
  o[4]  = fmaxf(acc[4]  + b1.x, 0.f); o[5]  = fmaxf(acc[5]  + b1.y, 0.f);
  o[6]  = fmaxf(acc[6]  + b1.z, 0.f); o[7]  = fmaxf(acc[7]  + b1.w, 0.f);
  o[8]  = fmaxf(acc[8]  + b2.x, 0.f); o[9]  = fmaxf(acc[9]  + b2.y, 0.f);
  o[10] = fmaxf(acc[10] + b2.z, 0.f); o[11] = fmaxf(acc[11] + b2.w, 0.f);
  o[12] = fmaxf(acc[12] + b3.x, 0.f); o[13] = fmaxf(acc[13] + b3.y, 0.f);
  o[14] = fmaxf(acc[14] + b3.z, 0.f); o[15] = fmaxf(acc[15] + b3.w, 0.f);

  if constexpr (!POOL) {
    ushortv8 r0, r1;
    #pragma unroll
    for (int j = 0; j < 8; ++j) { r0[j] = f2bf(o[j]); r1[j] = f2bf(o[8 + j]); }
    *(ushortv8*)(outp + (size_t)n * HD + lane * 16) = r0;
    *(ushortv8*)(outp + (size_t)n * HD + lane * 16 + 8) = r1;
  } else {
    __shared__ float pool[32][129];
    __shared__ int ib[32];
    int nl = t >> 3;
    #pragma unroll
    for (int j = 0; j < 16; ++j) pool[nl][lane * 16 + j] = o[j];
    if (t < 32) ib[t] = batch[blockIdx.x * 32 + t];
    __syncthreads();
    if (t < 128) {
      float a = 0.f;
      int c = t;
      #pragma unroll 4
      for (int i = 0; i < 32; ++i) {
        a += pool[i][c];
        if (i == 31 || ib[i + 1] != ib[i]) {
          atomicAdd(&sums[(size_t)ib[i] * HD + c], a);
          a = 0.f;
        }
      }
    }
  }
}

// ---------------- zero sums + counts ----------------
__global__ __launch_bounds__(256) void k_zero_counts(float* __restrict__ sums,
                                                     const int* __restrict__ batch,
                                                     float* __restrict__ cnt) {
  int i = blockIdx.x * blockDim.x + threadIdx.x;
  if (i < NB * HD) sums[i] = 0.f;
  if (blockIdx.x == 0 && threadIdx.x < NB) {
    int b = threadIdx.x;
    auto lb = [&](int v) {
      int lo = 0, hi = NN;
      while (lo < hi) { int m = (lo + hi) >> 1; if (batch[m] < v) lo = m + 1; else hi = m; }
      return lo;
    };
    cnt[b] = (float)(lb(b + 1) - lb(b));
  }
}

// ---------------- MLP head + softmax ----------------
__global__ __launch_bounds__(64) void k_head(const float* __restrict__ sums,
                                             const float* __restrict__ cnt,
                                             const float* __restrict__ W1,
                                             const float* __restrict__ b1,
                                             const float* __restrict__ W2,
                                             const float* __restrict__ b2,
                                             float* __restrict__ out) {
  int g = blockIdx.x, t = threadIdx.x;  // 64 threads
  __shared__ float gv[128];
  __shared__ float h[64];
  __shared__ float logits[2];
  float c = fmaxf(cnt[g], 1.0f);
  gv[t] = sums[g * HD + t] / c;
  gv[t + 64] = sums[g * HD + 64 + t] / c;
  __syncthreads();
  float acc = b1[t];
  for (int k = 0; k < 128; ++k) acc += gv[k] * W1[k * 64 + t];
  h[t] = fmaxf(acc, 0.f);
  __syncthreads();
  if (t < 2) {
    float a = b2[t];
    for (int j = 0; j < 64; ++j) a += h[j] * W2[j * 2 + t];
    logits[t] = a;
  }
  __syncthreads();
  if (t < 2) {
    float m = fmaxf(logits[0], logits[1]);
    float e0 = __expf(logits[0] - m), e1 = __expf(logits[1] - m);
    out[g * 2 + t] = (t == 0 ? e0 : e1) / (e0 + e1);
  }
}

// ---------------- launch ----------------
extern "C" void kernel_launch(void* const* d_in, const int* in_sizes, int n_in,
                              void* d_out, int out_size, void* d_ws, size_t ws_size,
                              hipStream_t stream) {
  const int*   x_idx = (const int*)d_in[0];
  const int*   eidx  = (const int*)d_in[1];
  const float* ew    = (const float*)d_in[2];
  const int*   batch = (const int*)d_in[3];
  const float* emb   = (const float*)d_in[4];
  const float* W1    = (const float*)d_in[5];
  const float* b1    = (const float*)d_in[6];
  const float* W2    = (const float*)d_in[7];
  const float* b2    = (const float*)d_in[8];
  const float* mW1   = (const float*)d_in[9];
  const float* mb1   = (const float*)d_in[10];
  const float* mW2   = (const float*)d_in[11];
  const float* mb2   = (const float*)d_in[12];
  const int* src = eidx;
  const int* dst = eidx + NE;
  float* out = (float*)d_out;

  char* ws = (char*)d_ws;
  size_t off = 0;
  auto alloc = [&](size_t bytes) {
    void* p = ws + off;
    off += (bytes + 255) & ~(size_t)255;
    return p;
  };
  int*   cntmat     = (int*)alloc((size_t)EBLK * NBUCK * 4);   // 1.6 MB
  int*   totals     = (int*)alloc((size_t)NBUCK * 4);
  int*   bucketBase = (int*)alloc((size_t)(NBUCK + 1) * 4);
  int*   rowptr     = (int*)alloc((size_t)(NN + 1) * 4);
  float* dinv       = (float*)alloc((size_t)NN * 4);
  unsigned* csrS    = (unsigned*)alloc((size_t)NE * 4);        // (src|norm)
  unsigned* csrV    = (unsigned*)alloc((size_t)NE * 4);        // (vocab|norm)
  unsigned short* Wt1  = (unsigned short*)alloc((size_t)HD * HD * 2);
  unsigned short* Wt2  = (unsigned short*)alloc((size_t)HD * HD * 2);
  unsigned char* embW  = (unsigned char*)alloc((size_t)NV * HD);   // fp8
  unsigned char* bufA  = (unsigned char*)alloc((size_t)NN * HD);   // fp8
  float* sums    = (float*)alloc((size_t)NB * HD * 4);
  float* cnt     = (float*)alloc((size_t)NB * 4);
  // union: spair (12.8MB) lives only until k_bfill; bufB (25.6MB) written after
  char* unionReg = (char*)alloc((size_t)NN * HD * 2);
  uint2* spair = (uint2*)unionReg;
  unsigned short* bufB = (unsigned short*)unionReg;

  // ---- CSR build via bucketed counting sort (zero global atomics) ----
  k_bcount<<<EBLK, 1024, 0, stream>>>(dst, cntmat);
  k_cscan<<<NBUCK, 256, 0, stream>>>(cntmat, totals);
  k_tscan<<<1, 1024, 0, stream>>>(totals, bucketBase);
  k_bscatter<<<EBLK, 1024, 0, stream>>>(src, dst, ew, cntmat, bucketBase, spair);
  k_bdeg<<<NBUCK, 256, 0, stream>>>(spair, bucketBase, rowptr, dinv);
  k_bfill<<<NBUCK, 256, 0, stream>>>(spair, bucketBase, rowptr, dinv, csrS);
  k_trans<<<(NE + 255) / 256, 256, 0, stream>>>(csrS, x_idx, csrV);

  // weight prep (transpose + bf16, both weights in one launch)
  k_wprep2<<<128, 256, 0, stream>>>(W1, W2, Wt1, Wt2);

  // embW = fp8(emb_table @ W1)
  k_gemm_mfma<true><<<(NV + 127) / 128, 256, 0, stream>>>(emb, Wt1, embW, NV);

  // zero sums + counts (before fused-pool agg)
  k_zero_counts<<<64, 256, 0, stream>>>(sums, batch, cnt);

  // conv1: bufB = bf16(relu(agg(embW via csrV) + b1))
  k_agg8<true, false><<<NN / 32, 256, 0, stream>>>(
      embW, x_idx, rowptr, csrV, dinv, b1, bufB, nullptr, nullptr);

  // conv2: bufA = fp8(h1 @ W2) ; fused agg+mean-pool partials into sums
  k_gemm_mfma<false><<<(NN + 127) / 128, 256, 0, stream>>>(bufB, Wt2, bufA, NN);
  k_agg8<false, true><<<NN / 32, 256, 0, stream>>>(
      bufA, nullptr, rowptr, csrS, dinv, b2, nullptr, batch, sums);

  // head
  k_head<<<NB, 64, 0, stream>>>(sums, cnt, mW1, mb1, mW2, mb2, out);
}

// Round 14
// 189.879 us; speedup vs baseline: 1.1634x; 1.0224x over previous
//
#include <hip/hip_runtime.h>
#include <hip/hip_bf16.h>

#define NN 100000      // nodes
#define NE 1600000     // edges
#define NB 128         // graphs
#define NV 10000       // vocab
#define HD 128         // emb = hid = 128

#define NBUCK 782      // ceil(NN/128) buckets, bucket = dst >> 7
#define EBLK 512       // edge blocks for bucket passes (1024 threads each)
#define EPB (NE / EBLK)  // 3125 edges per block (exact)

using bf16x8 = __attribute__((ext_vector_type(8))) short;
using f32x4  = __attribute__((ext_vector_type(4))) float;
typedef __attribute__((ext_vector_type(8))) unsigned short ushortv8;
typedef __attribute__((ext_vector_type(8))) unsigned char ucharv8;
typedef float f32x2 __attribute__((ext_vector_type(2)));

__device__ __forceinline__ float bf2f(unsigned short b) {
  return __uint_as_float((unsigned)b << 16);
}
__device__ __forceinline__ unsigned short f2bf(float f) {
  __hip_bfloat16 h = __float2bfloat16(f);   // RNE
  return *reinterpret_cast<unsigned short*>(&h);
}
// f32 -> fp8 e4m3 (OCP on gfx950), single value -> low byte
__device__ __forceinline__ unsigned char f2fp8(float f) {
  return (unsigned char)(__builtin_amdgcn_cvt_pk_fp8_f32(f, 0.f, 0, false) & 0xff);
}
// positive f32 -> 15-bit sign-less bf16; pack with id (vocab 14b or src 17b)
__device__ __forceinline__ unsigned packSN(unsigned s, float v) {
  return (s << 15) | ((unsigned)f2bf(v) & 0x7fffu);
}
__device__ __forceinline__ float unpackN(unsigned u) {
  return __uint_as_float((u & 0x7fffu) << 16);
}
// acc[0..15] += c * fp8x16(u)
__device__ __forceinline__ void acc16(float* acc, uint4 u, float c) {
  f32x2 v;
  v = __builtin_amdgcn_cvt_pk_f32_fp8((int)u.x, false); acc[0] += c*v[0]; acc[1] += c*v[1];
  v = __builtin_amdgcn_cvt_pk_f32_fp8((int)u.x, true);  acc[2] += c*v[0]; acc[3] += c*v[1];
  v = __builtin_amdgcn_cvt_pk_f32_fp8((int)u.y, false); acc[4] += c*v[0]; acc[5] += c*v[1];
  v = __builtin_amdgcn_cvt_pk_f32_fp8((int)u.y, true);  acc[6] += c*v[0]; acc[7] += c*v[1];
  v = __builtin_amdgcn_cvt_pk_f32_fp8((int)u.z, false); acc[8] += c*v[0]; acc[9] += c*v[1];
  v = __builtin_amdgcn_cvt_pk_f32_fp8((int)u.z, true);  acc[10]+= c*v[0]; acc[11]+= c*v[1];
  v = __builtin_amdgcn_cvt_pk_f32_fp8((int)u.w, false); acc[12]+= c*v[0]; acc[13]+= c*v[1];
  v = __builtin_amdgcn_cvt_pk_f32_fp8((int)u.w, true);  acc[14]+= c*v[0]; acc[15]+= c*v[1];
}

// ============ bucketed counting-sort CSR build (no global atomics) ============

__global__ __launch_bounds__(1024) void k_bcount(const int* __restrict__ dst,
                                                 int* __restrict__ cntmat) {
  __shared__ int h[NBUCK];
  int t = threadIdx.x, blk = blockIdx.x;
  for (int i = t; i < NBUCK; i += 1024) h[i] = 0;
  __syncthreads();
  int base = blk * EPB;
  for (int i = t; i < EPB; i += 1024) atomicAdd(&h[dst[base + i] >> 7], 1);
  __syncthreads();
  for (int i = t; i < NBUCK; i += 1024) cntmat[(size_t)blk * NBUCK + i] = h[i];
}

// per-bucket exclusive scan over EBLK=512 block counts (2 values/thread)
__global__ __launch_bounds__(256) void k_cscan(int* __restrict__ cntmat,
                                               int* __restrict__ totals) {
  __shared__ int sh[256];
  int bu = blockIdx.x, t = threadIdx.x;
  int v0 = cntmat[(size_t)(2 * t) * NBUCK + bu];
  int v1 = cntmat[(size_t)(2 * t + 1) * NBUCK + bu];
  int s = v0 + v1;
  sh[t] = s;
  __syncthreads();
  #pragma unroll
  for (int off = 1; off < 256; off <<= 1) {
    int u = (t >= off) ? sh[t - off] : 0;
    __syncthreads();
    sh[t] += u;
    __syncthreads();
  }
  int pre = sh[t] - s;
  cntmat[(size_t)(2 * t) * NBUCK + bu] = pre;
  cntmat[(size_t)(2 * t + 1) * NBUCK + bu] = pre + v0;
  if (t == 255) totals[bu] = sh[255];
}

// bucket-total scan + zero sums + graph counts (all 1-block-scale work)
__global__ __launch_bounds__(1024) void k_tscan(const int* __restrict__ totals,
                                                int* __restrict__ bucketBase,
                                                float* __restrict__ sums,
                                                const int* __restrict__ batch,
                                                float* __restrict__ cnt) {
  __shared__ int sh[1024];
  int t = threadIdx.x;
  int v = (t < NBUCK) ? totals[t] : 0;
  sh[t] = v;
  __syncthreads();
  #pragma unroll
  for (int off = 1; off < 1024; off <<= 1) {
    int u = (t >= off) ? sh[t - off] : 0;
    __syncthreads();
    sh[t] += u;
    __syncthreads();
  }
  if (t < NBUCK) bucketBase[t] = sh[t] - v;
  if (t == NBUCK - 1) bucketBase[NBUCK] = sh[t];   // = NE
  #pragma unroll
  for (int i = 0; i < 16; ++i) sums[t + i * 1024] = 0.f;   // 16384 = NB*HD
  if (t < NB) {
    auto lb = [&](int x) {
      int lo = 0, hi = NN;
      while (lo < hi) { int m = (lo + hi) >> 1; if (batch[m] < x) lo = m + 1; else hi = m; }
      return lo;
    };
    cnt[t] = (float)(lb(t + 1) - lb(t));
  }
}

// scatter edges into bucket-sorted array: one 8B store per edge
__global__ __launch_bounds__(1024) void k_bscatter(const int* __restrict__ src,
                                                   const int* __restrict__ dst,
                                                   const float* __restrict__ ew,
                                                   const int* __restrict__ cntmat,
                                                   const int* __restrict__ bucketBase,
                                                   uint2* __restrict__ spair) {
  __shared__ int off[NBUCK];
  int t = threadIdx.x, blk = blockIdx.x;
  for (int i = t; i < NBUCK; i += 1024)
    off[i] = bucketBase[i] + cntmat[(size_t)blk * NBUCK + i];
  __syncthreads();
  int base = blk * EPB;
  for (int i = t; i < EPB; i += 1024) {
    int e = base + i;
    int d = dst[e];
    unsigned pew = packSN((unsigned)src[e], ew[e]);
    int pos = atomicAdd(&off[d >> 7], 1);
    spair[pos] = make_uint2(pew, (unsigned)(d & 127));
  }
}

// fused deg+fill: one kernel, one logical pass over spair (2nd loop L2-hot).
// csr norm' = ew * dinv[dst]  (dinv[src] folded into k_trans / gemm2 epilogue)
__global__ __launch_bounds__(256) void k_bdegfill(const uint2* __restrict__ spair,
                                                  const int* __restrict__ bucketBase,
                                                  int* __restrict__ rowptr,
                                                  float* __restrict__ dinv,
                                                  unsigned* __restrict__ csr) {
  __shared__ int cnt[128];
  __shared__ float ws[128];
  __shared__ int sh[128];
  __shared__ float sdv[128];
  __shared__ int srp[128];
  int bu = blockIdx.x, t = threadIdx.x;
  if (t < 128) { cnt[t] = 0; ws[t] = 0.f; }
  __syncthreads();
  int ebeg = bucketBase[bu], eend = bucketBase[bu + 1];
  for (int e = ebeg + t; e < eend; e += 256) {
    uint2 p = spair[e];
    atomicAdd(&cnt[p.y], 1);
    atomicAdd(&ws[p.y], unpackN(p.x));
  }
  __syncthreads();
  int v = 0;
  if (t < 128) { v = cnt[t]; sh[t] = v; }
  __syncthreads();
  #pragma unroll
  for (int off = 1; off < 128; off <<= 1) {
    int u = 0;
    if (t < 128 && t >= off) u = sh[t - off];
    __syncthreads();
    if (t < 128) sh[t] += u;
    __syncthreads();
  }
  if (t < 128) {
    int gid = (bu << 7) + t;
    int rp = ebeg + sh[t] - v;
    float dv = rsqrtf(1.0f + ws[t]);
    srp[t] = rp;
    sdv[t] = dv;
    if (gid < NN) { rowptr[gid] = rp; dinv[gid] = dv; }
    if (gid == NN) rowptr[NN] = NE;   // bu=781, t=32
    cnt[t] = 0;                        // reuse as fill cursors
  }
  __syncthreads();
  for (int e = ebeg + t; e < eend; e += 256) {
    uint2 p = spair[e];
    int dl = (int)p.y;
    int r = atomicAdd(&cnt[dl], 1);
    float nrm = unpackN(p.x) * sdv[dl];          // ew * dinv[d]
    csr[srp[dl] + r] = packSN(p.x >> 15, nrm);
  }
}

// translate csrS (node id, norm') -> csrV (vocab id, full norm incl. dinv[src])
__global__ void k_trans(const unsigned* __restrict__ csrS,
                        const int* __restrict__ xidx,
                        const float* __restrict__ dinv,
                        unsigned* __restrict__ csrV) {
  int i = blockIdx.x * blockDim.x + threadIdx.x;
  if (i < NE) {
    unsigned u = csrS[i];
    unsigned s = u >> 15;
    float nrm = unpackN(u) * dinv[s];
    csrV[i] = packSN((unsigned)xidx[s], nrm);
  }
}

// ---------------- W prep: both weights in one launch ----------------
__global__ void k_wprep2(const float* __restrict__ W1, const float* __restrict__ W2,
                         unsigned short* __restrict__ Wt1, unsigned short* __restrict__ Wt2) {
  int t = blockIdx.x * blockDim.x + threadIdx.x;  // 32768
  const float* W = (t < 16384) ? W1 : W2;
  unsigned short* Wt = (t < 16384) ? Wt1 : Wt2;
  int i = t & 16383;
  int k = i >> 7, n = i & 127;
  Wt[n * 128 + k] = f2bf(W[k * 128 + n]);
}

// ---------------- MFMA GEMM: C[M,128] = A[M,128] @ W[128,128], out fp8 ----------------
// SCALE: multiply row r by dv[r] before fp8 encode (folds dinv[src] into features)
template <bool AF32, bool SCALE>
__global__ __launch_bounds__(256) void k_gemm_mfma(const void* __restrict__ Av,
                                                   const unsigned short* __restrict__ Wt,
                                                   unsigned char* __restrict__ C, int M,
                                                   const float* __restrict__ dv) {
  __shared__ unsigned char Cs[128][132];
  __shared__ float sdvv[128];
  const int t = threadIdx.x;
  const int wave = t >> 6, lane = t & 63;
  const int lrow = lane & 15, lk = lane >> 4;
  const int row0 = blockIdx.x * 128;
  const int wrow = row0 + wave * 32;

  if (SCALE) {
    if (t < 128) sdvv[t] = (row0 + t < M) ? dv[row0 + t] : 1.f;
    __syncthreads();
  }

  f32x4 acc[2][8];
  #pragma unroll
  for (int i = 0; i < 2; ++i)
    #pragma unroll
    for (int j = 0; j < 8; ++j) acc[i][j] = (f32x4){0.f, 0.f, 0.f, 0.f};

  #pragma unroll
  for (int kt = 0; kt < 4; ++kt) {
    bf16x8 a[2];
    #pragma unroll
    for (int rt = 0; rt < 2; ++rt) {
      int r = wrow + rt * 16 + lrow;
      bf16x8 av = (bf16x8){0, 0, 0, 0, 0, 0, 0, 0};
      if (r < M) {
        if (AF32) {
          const float* ap = (const float*)Av + (size_t)r * HD + kt * 32 + lk * 8;
          #pragma unroll
          for (int j = 0; j < 8; ++j) av[j] = (short)f2bf(ap[j]);
        } else {
          av = *(const bf16x8*)((const unsigned short*)Av + (size_t)r * HD + kt * 32 + lk * 8);
        }
      }
      a[rt] = av;
    }
    #pragma unroll
    for (int ct = 0; ct < 8; ++ct) {
      bf16x8 b = *(const bf16x8*)(Wt + (size_t)(ct * 16 + lrow) * HD + kt * 32 + lk * 8);
      acc[0][ct] = __builtin_amdgcn_mfma_f32_16x16x32_bf16(a[0], b, acc[0][ct], 0, 0, 0);
      acc[1][ct] = __builtin_amdgcn_mfma_f32_16x16x32_bf16(a[1], b, acc[1][ct], 0, 0, 0);
    }
  }

  #pragma unroll
  for (int rt = 0; rt < 2; ++rt)
    #pragma unroll
    for (int ct = 0; ct < 8; ++ct)
      #pragma unroll
      for (int reg = 0; reg < 4; ++reg) {
        int lr = wave * 32 + rt * 16 + lk * 4 + reg;
        float x = acc[rt][ct][reg];
        if (SCALE) x *= sdvv[lr];
        Cs[lr][ct * 16 + lrow] = f2fp8(x);
      }
  __syncthreads();

  #pragma unroll
  for (int i = 0; i < 8; ++i) {
    int idx = t + i * 256;       // 0..2047 uchar8 chunks
    int r = idx >> 4;
    int c = (idx & 15) * 8;
    int gr = row0 + r;
    if (gr < M)
      *(ucharv8*)(C + (size_t)gr * HD + c) = *(const ucharv8*)&Cs[r][c];
  }
}

// ---------------- pull aggregation, 8 lanes/node x 16B/lane ----------------
// csr pre-translated; per-edge chain csr -> gather. Quad loads software-pipelined.
// SCALED: xw rows carry dinv already -> self coef = dinv (else dinv^2).
// POOL: fused mean-pool partial (LDS run-reduce over sorted batch).
template <bool SELFIND, bool SCALED, bool POOL>
__global__ __launch_bounds__(256) void k_agg8(const unsigned char* __restrict__ xw,
                                              const int* __restrict__ xidx,
                                              const int* __restrict__ rowptr,
                                              const unsigned* __restrict__ csr,
                                              const float* __restrict__ dinv,
                                              const float* __restrict__ bias,
                                              unsigned short* __restrict__ outp,
                                              const int* __restrict__ batch,
                                              float* __restrict__ sums) {
  int t = threadIdx.x;
  int n = blockIdx.x * 32 + (t >> 3);   // grid exact: 3125*32 = NN
  int lane = t & 7;                     // cols [lane*16, lane*16+16)
  int beg = rowptr[n], end = rowptr[n + 1];

  int sn = SELFIND ? xidx[n] : n;
  uint4 uself = *(const uint4*)(xw + (size_t)sn * HD + lane * 16);

  float acc[16];
  #pragma unroll
  for (int j = 0; j < 16; ++j) acc[j] = 0.f;

  auto quad = [&](uint4 q) {
    int s0 = (int)(q.x >> 15), s1 = (int)(q.y >> 15);
    int s2 = (int)(q.z >> 15), s3 = (int)(q.w >> 15);
    uint4 u0 = *(const uint4*)(xw + (size_t)s0 * HD + lane * 16);
    uint4 u1 = *(const uint4*)(xw + (size_t)s1 * HD + lane * 16);
    uint4 u2 = *(const uint4*)(xw + (size_t)s2 * HD + lane * 16);
    uint4 u3 = *(const uint4*)(xw + (size_t)s3 * HD + lane * 16);
    acc16(acc, u0, unpackN(q.x)); acc16(acc, u1, unpackN(q.y));
    acc16(acc, u2, unpackN(q.z)); acc16(acc, u3, unpackN(q.w));
  };

  int e = beg;
  int alignEnd = min(end, (beg + 3) & ~3);
  for (; e < alignEnd; ++e) {           // align e to 4 for uint4 csr loads
    unsigned u = csr[e];
    int s0 = (int)(u >> 15);
    float c0 = unpackN(u);
    uint4 u0 = *(const uint4*)(xw + (size_t)s0 * HD + lane * 16);
    acc16(acc, u0, c0);
  }
  int nquad = (end - e) >> 2;
  if (nquad > 0) {                      // software-pipelined quads
    uint4 q = *(const uint4*)(csr + e);
    for (int i = 1; i < nquad; ++i) {
      uint4 qn = *(const uint4*)(csr + e + 4 * i);   // prefetch next quad
      quad(q);
      q = qn;
    }
    quad(q);
    e += nquad * 4;
  }
  for (; e < end; ++e) {                // <=3 scalar tail
    unsigned u = csr[e];
    int s0 = (int)(u >> 15);
    float c0 = unpackN(u);
    uint4 u0 = *(const uint4*)(xw + (size_t)s0 * HD + lane * 16);
    acc16(acc, u0, c0);
  }

  float d = dinv[n];
  acc16(acc, uself, SCALED ? d : d * d);

  const float4* bp = reinterpret_cast<const float4*>(bias + lane * 16);
  float4 b0 = bp[0], b1 = bp[1], b2 = bp[2], b3 = bp[3];
  float o[16];
  o[0]  = fmaxf(acc[0]  + b0.x, 0.f); o[1]  = fmaxf(acc[1]  + b0.y, 0.f);
  o[2]  = fmaxf(acc[2]  + b0.z, 0.f); o[3]  = fmaxf(acc[3]  + b0.w, 0.f);
  o[4]  = fmaxf(acc[4]  + b1.x, 0.f); o[5]  = fmaxf(acc[5]  + b1.y, 0.f);
  o[6]  = fmaxf(acc[6]  + b1.z, 0.f); o[7]  = fmaxf(acc[7]  + b1.w, 0.f);
  o[8]  = fmaxf(acc[8]  + b2.x, 0.f); o[9]  = fmaxf(acc[9]  + b2.y, 0.f);
  o[10] = fmaxf(acc[10] + b2.z, 0.f); o[11] = fmaxf(acc[11] + b2.w, 0.f);
  o[12] = fmaxf(acc[12] + b3.x, 0.f); o[13] = fmaxf(acc[13] + b3.y, 0.f);
  o[14] = fmaxf(acc[14] + b3.z, 0.f); o[15] = fmaxf(acc[15] + b3.w, 0.f);

  if constexpr (!POOL) {
    ushortv8 r0, r1;
    #pragma unroll
    for (int j = 0; j < 8; ++j) { r0[j] = f2bf(o[j]); r1[j] = f2bf(o[8 + j]); }
    *(ushortv8*)(outp + (size_t)n * HD + lane * 16) = r0;
    *(ushortv8*)(outp + (size_t)n * HD + lane * 16 + 8) = r1;
  } else {
    __shared__ float pool[32][129];
    __shared__ int ib[32];
    int nl = t >> 3;
    #pragma unroll
    for (int j = 0; j < 16; ++j) pool[nl][lane * 16 + j] = o[j];
    if (t < 32) ib[t] = batch[blockIdx.x * 32 + t];
    __syncthreads();
    if (t < 128) {
      float a = 0.f;
      int c = t;
      #pragma unroll 4
      for (int i = 0; i < 32; ++i) {
        a += pool[i][c];
        if (i == 31 || ib[i + 1] != ib[i]) {
          atomicAdd(&sums[(size_t)ib[i] * HD + c], a);
          a = 0.f;
        }
      }
    }
  }
}

// ---------------- MLP head + softmax ----------------
__global__ __launch_bounds__(64) void k_head(const float* __restrict__ sums,
                                             const float* __restrict__ cnt,
                                             const float* __restrict__ W1,
                                             const float* __restrict__ b1,
                                             const float* __restrict__ W2,
                                             const float* __restrict__ b2,
                                             float* __restrict__ out) {
  int g = blockIdx.x, t = threadIdx.x;  // 64 threads
  __shared__ float gv[128];
  __shared__ float h[64];
  __shared__ float logits[2];
  float c = fmaxf(cnt[g], 1.0f);
  gv[t] = sums[g * HD + t] / c;
  gv[t + 64] = sums[g * HD + 64 + t] / c;
  __syncthreads();
  float acc = b1[t];
  for (int k = 0; k < 128; ++k) acc += gv[k] * W1[k * 64 + t];
  h[t] = fmaxf(acc, 0.f);
  __syncthreads();
  if (t < 2) {
    float a = b2[t];
    for (int j = 0; j < 64; ++j) a += h[j] * W2[j * 2 + t];
    logits[t] = a;
  }
  __syncthreads();
  if (t < 2) {
    float m = fmaxf(logits[0], logits[1]);
    float e0 = __expf(logits[0] - m), e1 = __expf(logits[1] - m);
    out[g * 2 + t] = (t == 0 ? e0 : e1) / (e0 + e1);
  }
}

// ---------------- launch ----------------
extern "C" void kernel_launch(void* const* d_in, const int* in_sizes, int n_in,
                              void* d_out, int out_size, void* d_ws, size_t ws_size,
                              hipStream_t stream) {
  const int*   x_idx = (const int*)d_in[0];
  const int*   eidx  = (const int*)d_in[1];
  const float* ew    = (const float*)d_in[2];
  const int*   batch = (const int*)d_in[3];
  const float* emb   = (const float*)d_in[4];
  const float* W1    = (const float*)d_in[5];
  const float* b1    = (const float*)d_in[6];
  const float* W2    = (const float*)d_in[7];
  const float* b2    = (const float*)d_in[8];
  const float* mW1   = (const float*)d_in[9];
  const float* mb1   = (const float*)d_in[10];
  const float* mW2   = (const float*)d_in[11];
  const float* mb2   = (const float*)d_in[12];
  const int* src = eidx;
  const int* dst = eidx + NE;
  float* out = (float*)d_out;

  char* ws = (char*)d_ws;
  size_t off = 0;
  auto alloc = [&](size_t bytes) {
    void* p = ws + off;
    off += (bytes + 255) & ~(size_t)255;
    return p;
  };
  int*   cntmat     = (int*)alloc((size_t)EBLK * NBUCK * 4);   // 1.6 MB
  int*   totals     = (int*)alloc((size_t)NBUCK * 4);
  int*   bucketBase = (int*)alloc((size_t)(NBUCK + 1) * 4);
  int*   rowptr     = (int*)alloc((size_t)(NN + 1) * 4);
  float* dinv       = (float*)alloc((size_t)NN * 4);
  unsigned* csrS    = (unsigned*)alloc((size_t)NE * 4);        // (src | ew*dinv[d])
  unsigned* csrV    = (unsigned*)alloc((size_t)NE * 4);        // (vocab | full norm)
  unsigned short* Wt1  = (unsigned short*)alloc((size_t)HD * HD * 2);
  unsigned short* Wt2  = (unsigned short*)alloc((size_t)HD * HD * 2);
  unsigned char* embW  = (unsigned char*)alloc((size_t)NV * HD);   // fp8
  unsigned char* bufA  = (unsigned char*)alloc((size_t)NN * HD);   // fp8, dinv-scaled
  float* sums    = (float*)alloc((size_t)NB * HD * 4);
  float* cnt     = (float*)alloc((size_t)NB * 4);
  // union: spair (12.8MB) lives only until k_bdegfill; bufB (25.6MB) written after
  char* unionReg = (char*)alloc((size_t)NN * HD * 2);
  uint2* spair = (uint2*)unionReg;
  unsigned short* bufB = (unsigned short*)unionReg;

  // ---- CSR build via bucketed counting sort (zero global atomics) ----
  k_bcount<<<EBLK, 1024, 0, stream>>>(dst, cntmat);
  k_cscan<<<NBUCK, 256, 0, stream>>>(cntmat, totals);
  k_tscan<<<1, 1024, 0, stream>>>(totals, bucketBase, sums, batch, cnt);
  k_bscatter<<<EBLK, 1024, 0, stream>>>(src, dst, ew, cntmat, bucketBase, spair);
  k_bdegfill<<<NBUCK, 256, 0, stream>>>(spair, bucketBase, rowptr, dinv, csrS);
  k_trans<<<(NE + 255) / 256, 256, 0, stream>>>(csrS, x_idx, dinv, csrV);

  // weight prep (transpose + bf16, both weights in one launch)
  k_wprep2<<<128, 256, 0, stream>>>(W1, W2, Wt1, Wt2);

  // embW = fp8(emb_table @ W1)
  k_gemm_mfma<true, false><<<(NV + 127) / 128, 256, 0, stream>>>(
      emb, Wt1, embW, NV, nullptr);

  // conv1: bufB = bf16(relu(agg(embW via csrV) + b1)); self coef dinv^2
  k_agg8<true, false, false><<<NN / 32, 256, 0, stream>>>(
      embW, x_idx, rowptr, csrV, dinv, b1, bufB, nullptr, nullptr);

  // conv2: bufA = fp8(dinv[n] * (h1 @ W2)) ; agg uses norm'=ew*dinv[d]; self coef dinv
  k_gemm_mfma<false, true><<<(NN + 127) / 128, 256, 0, stream>>>(
      bufB, Wt2, bufA, NN, dinv);
  k_agg8<false, true, true><<<NN / 32, 256, 0, stream>>>(
      bufA, nullptr, rowptr, csrS, dinv, b2, nullptr, batch, sums);

  // head
  k_head<<<NB, 64, 0, stream>>>(sums, cnt, mW1, mb1, mW2, mb2, out);
}